// Round 4
// baseline (428.448 us; speedup 1.0000x reference)
//
#include <hip/hip_runtime.h>
#include <math.h>

#define HSZ   4096
#define RROWS 64             // k-rows per block
#define NSLAB 64             // HSZ / RROWS
#define NCT   4              // column quarter-tiles (1024 cols each)

struct WPtrs { const float* W[8]; };
struct BPtrs { const float* b[8]; };

__device__ __forceinline__ void fma4(float4& a, float s, const float4& w) {
    a.x = fmaf(s, w.x, a.x);
    a.y = fmaf(s, w.y, a.y);
    a.z = fmaf(s, w.z, a.z);
    a.w = fmaf(s, w.w, a.w);
}

// --- stage 1: per-slab partial GEMV -----------------------------------------
// Block (mat, slab, ct): 64 rows x 1024 cols of W[mat]. x-side writes partials
// px[slab][mat][col] (no atomics). h-side early-exits on an all-zero h chunk,
// else atomically accumulates into hg. Double-buffered 8-deep float4 prefetch
// keeps 8-16 global loads in flight per wave (launch_bounds(256,4) -> 128 VGPR
// cap). All buffer indices are compile-time constants after full unroll.
__global__ __launch_bounds__(256, 4) void lstm_gemv_kernel(
        WPtrs wp, const float* __restrict__ x, const float* __restrict__ hv,
        float* __restrict__ px, float* __restrict__ hg) {
    const int mat  = blockIdx.x & 7;             // interleave x/h so h exits early
    const int rem  = blockIdx.x >> 3;            // 0..255
    const int slab = rem >> 2;                   // 0..63
    const int ct   = rem & 3;                    // 0..3
    const int tid  = threadIdx.x;
    const float* __restrict__ v = (mat < 4) ? x : hv;

    __shared__ float vs[RROWS];
    __shared__ int nz;
    if (tid == 0) nz = 0;
    __syncthreads();
    if (tid < 64) {                              // wave 0 only (wave size 64)
        float val = v[slab * RROWS + tid];
        vs[tid] = val;
        if (__any(val != 0.0f) && tid == 0) nz = 1;
    }
    __syncthreads();
    if (mat >= 4 && !nz) return;                 // zero h chunk -> skip weights

    const int col = ct * 1024 + tid * 4;
    const float* __restrict__ Wp =
        wp.W[mat] + (size_t)slab * RROWS * HSZ + col;
    float4 acc = make_float4(0.f, 0.f, 0.f, 0.f);

    float4 cur[8], nxt[8];
#pragma unroll
    for (int u = 0; u < 8; ++u)
        cur[u] = *(const float4*)(Wp + (size_t)u * HSZ);
#pragma unroll
    for (int g = 0; g < 8; ++g) {
        if (g < 7) {
#pragma unroll
            for (int u = 0; u < 8; ++u)
                nxt[u] = *(const float4*)(Wp + (size_t)((g + 1) * 8 + u) * HSZ);
        }
#pragma unroll
        for (int u = 0; u < 8; ++u)
            fma4(acc, vs[g * 8 + u], cur[u]);
        if (g < 7) {
#pragma unroll
            for (int u = 0; u < 8; ++u)
                cur[u] = nxt[u];                 // register rename after unroll
        }
    }

    if (mat < 4) {
        float* dst = px + ((size_t)slab * 4 + mat) * HSZ + col;
        *(float4*)dst = acc;
    } else {
        float* dst = hg + (size_t)(mat - 4) * HSZ + col;
        atomicAdd(dst + 0, acc.x); atomicAdd(dst + 1, acc.y);
        atomicAdd(dst + 2, acc.z); atomicAdd(dst + 3, acc.w);
    }
}

// --- stage 2: fold 64 slab-partials + h + biases, then activations ----------
// 64 blocks, one 64-wide j tile each. Threads: (jl 0..63, slab-group 0..3).
__device__ __forceinline__ float sigmoidf_fast(float v) {
    return 1.0f / (1.0f + __expf(-v));
}

__global__ __launch_bounds__(256) void lstm_reduce_final_kernel(
        const float* __restrict__ px, const float* __restrict__ hg,
        BPtrs bp, const float* __restrict__ c, float* __restrict__ out) {
    const int j0 = blockIdx.x * 64;
    const int jl = threadIdx.x & 63;
    const int sg = threadIdx.x >> 6;             // 0..3 (16 slabs each)
    __shared__ float red[4][4][64];              // [m][sg][jl]
#pragma unroll
    for (int m = 0; m < 4; ++m) {
        const float* p = px + ((size_t)(sg * 16) * 4 + m) * HSZ + j0 + jl;
        float s0 = 0.f, s1 = 0.f;
#pragma unroll
        for (int i = 0; i < 16; i += 2) {
            s0 += p[(size_t)(i + 0) * 4 * HSZ];
            s1 += p[(size_t)(i + 1) * 4 * HSZ];
        }
        red[m][sg][jl] = s0 + s1;
    }
    __syncthreads();
    if (threadIdx.x < 64) {
        const int j = j0 + jl;
        float g[4];
#pragma unroll
        for (int m = 0; m < 4; ++m)
            g[m] = red[m][0][jl] + red[m][1][jl] + red[m][2][jl] + red[m][3][jl]
                 + hg[m * HSZ + j] + bp.b[m][j] + bp.b[m + 4][j];
        float it = sigmoidf_fast(g[0]);
        float ft = sigmoidf_fast(g[1]);
        float gt = tanhf(g[2]);
        float ot = sigmoidf_fast(g[3]);
        float cn = ft * c[j] + it * gt;
        out[j] = ot * tanhf(cn);
    }
}

extern "C" void kernel_launch(void* const* d_in, const int* in_sizes, int n_in,
                              void* d_out, int out_size, void* d_ws, size_t ws_size,
                              hipStream_t stream) {
    const float* x = (const float*)d_in[0];
    WPtrs wp;
    for (int i = 0; i < 8; ++i) wp.W[i] = (const float*)d_in[1 + i];   // Wii..Who
    BPtrs bp;
    for (int i = 0; i < 8; ++i) bp.b[i] = (const float*)d_in[9 + i];   // bii..bho
    const float* h = (const float*)d_in[17];
    const float* c = (const float*)d_in[18];

    float* px = (float*)d_ws;                    // [64][4][4096] = 4 MB partials
    float* hg = px + (size_t)NSLAB * 4 * HSZ;    // [4][4096] h-side accumulators

    hipMemsetAsync(hg, 0, 4 * HSZ * sizeof(float), stream);
    lstm_gemv_kernel<<<8 * NSLAB * NCT, 256, 0, stream>>>(wp, x, h, px, hg);
    lstm_reduce_final_kernel<<<HSZ / 64, 256, 0, stream>>>(px, hg, bp, c,
                                                           (float*)d_out);
}